// Round 8
// baseline (107.525 us; speedup 1.0000x reference)
//
#include <hip/hip_runtime.h>

// CalcSpixelFeats R27. Base = R26 (104.2us total, new best; mfma ~20us,
// reduce ~7us, divide ~3us inferred — all below the rocprof top-5 cutoff,
// which is now dominated by the harness's own 268MB ws-poison fills).
// R26 post-mortem: R25 theory confirmed (finalize 65->~10us). Residuals:
//  1) mfma prefetch depth 1 covers ~300cy of a ~900cy HBM latency -> chunks
//     stall in lockstep. R27: depth-2 prefetch with two static register sets
//     (A/B), manually 2-unrolled chunk loop (cpb always even).
//  2) Phase Z rewrote 32KB LDS per chunk. R27: scatter-UNZERO — each thread
//     zeroes the <=3 slots it wrote (distinct by construction: slot encodes
//     pixel lane; j's of one pixel hit distinct bins). Full zero once.
//  3) reduce+divide fused: block=(b, 4-bin group)=132 consecutive floats,
//     wave-coalesced 256B loads over partials, LDS combine, divide, write.
// index_map is uniform-random over K (reference setup) -> no bin locality
// exists; dense 256x64 A-tile is the right shape.

#define CCH  32
#define KMAX 256
#define FST  (CCH + 1)       // 33
#define KFS  (KMAX * FST)    // 8448 floats per block-partial

typedef __attribute__((ext_vector_type(4))) int   int4v;
typedef __attribute__((ext_vector_type(4))) float f32x4;

__device__ __forceinline__ unsigned pack_bf16(float a, float b) {
    unsigned ua = __float_as_uint(a);
    unsigned ub = __float_as_uint(b);
    ua = (ua + 0x7FFFu + ((ua >> 16) & 1u)) >> 16;   // RNE
    ub = (ub + 0x7FFFu + ((ub >> 16) & 1u)) >> 16;
    return ua | (ub << 16);
}
__device__ __forceinline__ unsigned short bf16_1(float a) {
    unsigned ua = __float_as_uint(a);
    return (unsigned short)((ua + 0x7FFFu + ((ua >> 16) & 1u)) >> 16);
}

__device__ __forceinline__ void wg_barrier() {
    // LDS-visibility barrier WITHOUT the __syncthreads vmcnt(0) drain:
    // prefetched global loads (register destinations) stay in flight.
    asm volatile("s_waitcnt lgkmcnt(0)" ::: "memory");
    __builtin_amdgcn_s_barrier();
}

// A slot for A[t][p] (t bin 0..255, p px 0..63): region=(t>>4)*2+(p>>5),
// q=p&31, lane=(t&15)+16*(q>>3), elem=q&7. B slot for B[p][c]:
// region=(c>>4)*2+(p>>5), lane=(c&15)+16*(q>>3), elem=q&7.

// ---- chunk-phase macros (static register names; rule #20) ----

#define PF_CHUNK(CH, IDXR, WV0, WV1, WV2, FV0, FV1, FV2, FV3)               \
    {                                                                       \
        const int p0n = (blkb * cpb + (CH)) * 64;                           \
        IDXR = ix_b[p0n + pl];                                              \
        WV0 = as_b[(size_t)grp * P + p0n + pl];                             \
        WV1 = as_b[(size_t)(grp + 4) * P + p0n + pl];                       \
        WV2 = (grp == 0) ? as_b[(size_t)8 * P + p0n + pl] : 0.f;            \
        FV0 = *(const float2*)&pf_b[(size_t)(cg     ) * P + p0n + 2 * pp];  \
        FV1 = *(const float2*)&pf_b[(size_t)(cg +  8) * P + p0n + 2 * pp];  \
        FV2 = *(const float2*)&pf_b[(size_t)(cg + 16) * P + p0n + 2 * pp];  \
        FV3 = *(const float2*)&pf_b[(size_t)(cg + 24) * P + p0n + 2 * pp];  \
    }

#define SCATTER_STAGE(IDXR, WV0, WV1, WV2, FV0, FV1, FV2, FV3, O0, O1, O2)  \
    {                                                                       \
        const int iy  = (IDXR) / nw;                                        \
        const int ixx = (IDXR) - iy * nw;                                   \
        const float wvv[3] = {WV0, WV1, WV2};                               \
        int offs[3] = {-1, -1, -1};                                         \
        _Pragma("unroll")                                                   \
        for (int wi = 0; wi < 3; ++wi) {                                    \
            const int j = grp + 4 * wi;                                     \
            if (j >= 9) continue;                                           \
            const int ty = iy + j / 3 - 1;                                  \
            const int tx = ixx + j % 3 - 1;                                 \
            if (tx < 0 || tx >= nw || ty < 0 || ty >= nh) continue;         \
            const int t   = ty * nw + tx;                                   \
            const int off = ((((t >> 4) * 2 + ps_) * 64                     \
                              + (t & 15) + ((q >> 3) << 4)) * 8) + (q & 7); \
            lsA[off] = (short)bf16_1(wvv[wi]);                              \
            offs[wi] = off;                                                 \
        }                                                                   \
        O0 = offs[0]; O1 = offs[1]; O2 = offs[2];                           \
        const float2 fvv[4] = {FV0, FV1, FV2, FV3};                         \
        _Pragma("unroll")                                                   \
        for (int ci = 0; ci < 4; ++ci) {                                    \
            const int c   = cg + 8 * ci;                                    \
            const int off = ((((c >> 4) * 2 + (p2 >> 5)) * 64               \
                              + (c & 15) + ((q2 >> 3) << 4)) * 8) + (q2&7); \
            *(unsigned*)&lsB[off] = pack_bf16(fvv[ci].x, fvv[ci].y);        \
        }                                                                   \
    }

#define MFMA_PHASE()                                                        \
    _Pragma("unroll")                                                       \
    for (int ps = 0; ps < 2; ++ps) {                                        \
        int4v bfr[3];                                                       \
        _Pragma("unroll")                                                   \
        for (int ct = 0; ct < 3; ++ct)                                      \
            bfr[ct] = *(int4v*)&lsB[((ct * 2 + ps) * 64 + lane) * 8];       \
        _Pragma("unroll")                                                   \
        for (int ktl = 0; ktl < 4; ++ktl) {                                 \
            const int kt = wave * 4 + ktl;                                  \
            int4v af = *(int4v*)&lsA[((kt * 2 + ps) * 64 + lane) * 8];      \
            _Pragma("unroll")                                               \
            for (int ct = 0; ct < 3; ++ct) {                                \
                asm("v_mfma_f32_16x16x32_bf16 %0, %1, %2, %0"               \
                    : "+v"(acc[ktl][ct])                                    \
                    : "v"(af), "v"(bfr[ct]));                               \
            }                                                               \
        }                                                                   \
    }

#define UNZERO(O0, O1, O2)                                                  \
    { if ((O0) >= 0) lsA[O0] = 0; if ((O1) >= 0) lsA[O1] = 0;               \
      if ((O2) >= 0) lsA[O2] = 0; }

__global__ __launch_bounds__(256, 4) void spx_mfma_kernel(
    const float* __restrict__ pf,      // [B][C][P]
    const float* __restrict__ assoc,   // [B][9][P]
    const int*   __restrict__ idxmap,  // [B][P]
    const int*   __restrict__ nw_p,
    const int*   __restrict__ nh_p,
    float*       __restrict__ part,    // [B*bpbk][KFS] block partials
    int P, int K, int cpb, int bpbk)   // chunks/block (EVEN), blocks/batch
{
    __shared__ __align__(16) short lsA[16 * 2 * 64 * 8];  // 32 KB
    __shared__ __align__(16) short lsB[6 * 64 * 8];       // 6 KB

    const int tid  = threadIdx.x;
    const int wave = tid >> 6;
    const int lane = tid & 63;
    const int b    = blockIdx.x / bpbk;
    const int blkb = blockIdx.x - b * bpbk;

    const int nw = nw_p[0], nh = nh_p[0];

    // prologue: full zero of lsA (ONCE — per-chunk re-zero replaced by
    // scatter-unzero), static ones-region of lsB
#pragma unroll
    for (int i = 0; i < 8; ++i)
        *(uint4*)&lsA[(tid + 256 * i) * 8] = make_uint4(0u, 0u, 0u, 0u);
    if (tid < 128) {
        const int reg = 4 + (tid >> 6);
        const int ln  = tid & 63;
        uint4 v = ((ln & 15) == 0)
            ? make_uint4(0x3F803F80u, 0x3F803F80u, 0x3F803F80u, 0x3F803F80u)
            : make_uint4(0u, 0u, 0u, 0u);
        *(uint4*)&lsB[(reg * 64 + ln) * 8] = v;
    }

    const int*   ix_b = idxmap + (size_t)b * P;
    const float* pf_b = pf     + (size_t)b * CCH * P;
    const float* as_b = assoc  + (size_t)b * 9 * P;

    f32x4 acc[4][3];
#pragma unroll
    for (int i = 0; i < 4; ++i)
#pragma unroll
        for (int j = 0; j < 3; ++j) acc[i][j] = f32x4{0.f, 0.f, 0.f, 0.f};

    const int grp = tid >> 6;      // j-group 0..3
    const int pl  = tid & 63;      // scatter pixel lane
    const int pp  = tid & 31;      // pixel-pair index for F staging
    const int cg  = tid >> 5;      // channel group 0..7
    const int q   = pl & 31;
    const int ps_ = pl >> 5;
    const int p2  = 2 * pp;
    const int q2  = p2 & 31;

    // depth-2 prefetch: two static register sets
    int    idxA, idxB2;
    float  wA0, wA1, wA2, wB0, wB1, wB2;
    float2 fA0, fA1, fA2, fA3, fB0, fB1, fB2, fB3;
    int    oA0, oA1, oA2, oB0, oB1, oB2;

    PF_CHUNK(0, idxA, wA0, wA1, wA2, fA0, fA1, fA2, fA3);
    PF_CHUNK(1, idxB2, wB0, wB1, wB2, fB0, fB1, fB2, fB3);

    wg_barrier();   // zero + ones visible before first scatter

    for (int ch = 0; ch < cpb; ch += 2) {
        // ---- even chunk (set A) ----
        SCATTER_STAGE(idxA, wA0, wA1, wA2, fA0, fA1, fA2, fA3, oA0, oA1, oA2);
        {   // issue prefetch for ch+2 (consumed 2 chunk-pipelines later)
            const int chn = (ch + 2 < cpb) ? ch + 2 : cpb - 1;
            PF_CHUNK(chn, idxA, wA0, wA1, wA2, fA0, fA1, fA2, fA3);
        }
        wg_barrier();
        MFMA_PHASE();
        wg_barrier();
        UNZERO(oA0, oA1, oA2);
        wg_barrier();

        // ---- odd chunk (set B) ----
        SCATTER_STAGE(idxB2, wB0, wB1, wB2, fB0, fB1, fB2, fB3, oB0, oB1, oB2);
        {
            const int chn = (ch + 3 < cpb) ? ch + 3 : cpb - 1;
            PF_CHUNK(chn, idxB2, wB0, wB1, wB2, fB0, fB1, fB2, fB3);
        }
        wg_barrier();
        MFMA_PHASE();
        wg_barrier();
        UNZERO(oB0, oB1, oB2);
        wg_barrier();
    }

    // MFMA -> VALU read hazard guard before the flush reads acc
    asm volatile("s_nop 7\n\ts_nop 7");

    // flush: plain streaming stores of this block's partial (no atomics)
    float* pb = part + (size_t)(b * bpbk + blkb) * KFS;
    const int col = lane & 15;
    const int rw0 = (lane >> 4) * 4;
#pragma unroll
    for (int ktl = 0; ktl < 4; ++ktl) {
        const int kt = wave * 4 + ktl;
#pragma unroll
        for (int ct = 0; ct < 3; ++ct) {
            const int c = ct * 16 + col;
            if (c > CCH) continue;      // ct=2: only col 0 (wsum) is real
#pragma unroll
            for (int i = 0; i < 4; ++i) {
                const int k = kt * 16 + rw0 + i;
                pb[(size_t)k * FST + c] = acc[ktl][ct][i];
            }
        }
    }
}

// Fused reduce+divide. Block (b,g) owns 4 bins = 132 consecutive floats
// (132*64 == KFS). Wave w lane l sums cols {l, 64+l, 128+l(<4)} over
// partials blk = w+4m (256B coalesced wave-loads, 6 loads in flight via
// 2-unroll), LDS cross-wave combine, then in-block division + out write.
__global__ __launch_bounds__(256) void spx_reduce_div_kernel(
    const float* __restrict__ part,   // [B*bpbk][KFS]
    float*       __restrict__ out,    // [B][C][K]
    int K, int bpbk)
{
    __shared__ float red[4][4 * FST];  // [wave][132]

    const int gpb = KMAX / 4;          // 64 groups per batch
    const int b   = blockIdx.x / gpb;
    const int g   = blockIdx.x - b * gpb;
    const int w   = threadIdx.x >> 6;
    const int l   = threadIdx.x & 63;

    const float* p = part + (size_t)b * bpbk * KFS + g * (4 * FST);
    const int n = bpbk >> 2;           // partials per wave
    float s0 = 0.f, s1 = 0.f, s2 = 0.f;
    for (int m = 0; m < n; m += 2) {
        const float* r0 = p + (size_t)(w + 4 * m) * KFS;
        const float* r1 = p + (size_t)(w + 4 * (m + 1)) * KFS;
        const float a0 = r0[l], a1 = r0[64 + l];
        const float a2 = (l < 4) ? r0[128 + l] : 0.f;
        const float b0 = r1[l], b1 = r1[64 + l];
        const float b2 = (l < 4) ? r1[128 + l] : 0.f;
        s0 += a0 + b0; s1 += a1 + b1; s2 += a2 + b2;
    }
    red[w][l] = s0;
    red[w][64 + l] = s1;
    if (l < 4) red[w][128 + l] = s2;
    __syncthreads();

    if (threadIdx.x < 128) {
        const int c  = threadIdx.x >> 2;   // 0..31
        const int lb = threadIdx.x & 3;    // local bin 0..3
        const float W = red[0][lb * FST + CCH] + red[1][lb * FST + CCH]
                      + red[2][lb * FST + CCH] + red[3][lb * FST + CCH];
        const float v = red[0][lb * FST + c] + red[1][lb * FST + c]
                      + red[2][lb * FST + c] + red[3][lb * FST + c];
        out[((size_t)b * CCH + c) * K + g * 4 + lb] =
            (W > 1e-16f) ? v / W : 0.f;
    }
}

extern "C" void kernel_launch(void* const* d_in, const int* in_sizes, int n_in,
                              void* d_out, int out_size, void* d_ws, size_t ws_size,
                              hipStream_t stream) {
    const float* pf     = (const float*)d_in[0];
    const float* assoc  = (const float*)d_in[1];
    const int*   idxmap = (const int*)d_in[2];
    const int*   nw_p   = (const int*)d_in[3];
    const int*   nh_p   = (const int*)d_in[4];
    float* out = (float*)d_out;

    const int BP = in_sizes[2];          // B*P = 262144
    const int B  = 4;                    // fixed by reference setup
    const int P  = BP / B;               // 65536
    const int K  = out_size / (B * CCH); // 256 (== KMAX)

    // ws: part [B*bpbk][KFS] only (no fsum buffer, no memset)
    int bpbk = 256;                      // 1024 blocks -> 4 blocks/CU
    while ((size_t)B * bpbk * KFS * sizeof(float) > ws_size && bpbk > 64)
        bpbk >>= 1;
    const int cpb = (P / 64) / bpbk;     // 4 (even; fallbacks 8/16 even too)
    float* part = (float*)d_ws;

    spx_mfma_kernel<<<B * bpbk, 256, 0, stream>>>(
        pf, assoc, idxmap, nw_p, nh_p, part, P, K, cpb, bpbk);

    spx_reduce_div_kernel<<<B * (KMAX / 4), 256, 0, stream>>>(
        part, out, K, bpbk);
}

// Round 9
// 103.754 us; speedup vs baseline: 1.0364x; 1.0364x over previous
//
#include <hip/hip_runtime.h>

// CalcSpixelFeats R28. Base = R27 (107.5us; R26 104.2 remains best).
// R27 post-mortem: bundle was net-neutral — unzero still cost a 3rd barrier
// interval per chunk, so nothing structural actually changed. R28 is the
// structural round:
//  1) READER-ZERO: each A-region is read by exactly one wave -> that wave
//     writes b128 zeros back right after its fragment read (same-wave DS
//     ordering makes this race-free). Zero interval GONE -> 2 barriers/chunk.
//  2) 128-px chunks, 512-thread blocks, bpbk=128: barriers/pixel halved
//     again (9 drains per 512 px vs 12 per 256), partials round-trip halved
//     (34.6 -> 17.3 MB). LDS 64KB A + 12KB B = 76KB -> 2 blocks/CU x 8 waves
//     = 16 waves/CU (unchanged wave count). acc 48->24 VGPRs pays for the
//     depth-2 prefetch sets; __launch_bounds__(512,4) caps VGPR at 128.
// Fragment math identical to the verified R23-R27 core (SPS 2 -> 4).

#define CCH  32
#define KMAX 256
#define FST  (CCH + 1)       // 33
#define KFS  (KMAX * FST)    // 8448 floats per block-partial
#define PXC  128             // pixels per chunk
#define SPS  (PXC / 32)      // 4 px-subtiles per chunk

typedef __attribute__((ext_vector_type(4))) int   int4v;
typedef __attribute__((ext_vector_type(4))) float f32x4;

__device__ __forceinline__ unsigned pack_bf16(float a, float b) {
    unsigned ua = __float_as_uint(a);
    unsigned ub = __float_as_uint(b);
    ua = (ua + 0x7FFFu + ((ua >> 16) & 1u)) >> 16;   // RNE
    ub = (ub + 0x7FFFu + ((ub >> 16) & 1u)) >> 16;
    return ua | (ub << 16);
}
__device__ __forceinline__ unsigned short bf16_1(float a) {
    unsigned ua = __float_as_uint(a);
    return (unsigned short)((ua + 0x7FFFu + ((ua >> 16) & 1u)) >> 16);
}

__device__ __forceinline__ void wg_barrier() {
    // LDS-visibility barrier WITHOUT the __syncthreads vmcnt(0) drain:
    // prefetched global loads (register destinations) stay in flight.
    asm volatile("s_waitcnt lgkmcnt(0)" ::: "memory");
    __builtin_amdgcn_s_barrier();
}

// A slot for A[t][p] (t bin 0..255, p px 0..PXC-1): region=(t>>4)*SPS+(p>>5),
// q=p&31, lane=(t&15)+16*(q>>3), elem=q&7. B slot for B[p][c]:
// region=(c>>4)*SPS+(p>>5), same lane/elem mapping. Region = 64 lanes x 16B.

#define PF_CHUNK(CH, IDXR, WV0, WV1, WV2, FV0, FV1, FV2, FV3)               \
    {                                                                       \
        const int p0n = (blkb * cpb + (CH)) * PXC;                          \
        IDXR = ix_b[p0n + pl];                                              \
        WV0 = as_b[(size_t)grp * P + p0n + pl];                             \
        WV1 = as_b[(size_t)(grp + 4) * P + p0n + pl];                       \
        WV2 = (grp == 0) ? as_b[(size_t)8 * P + p0n + pl] : 0.f;            \
        FV0 = *(const float2*)&pf_b[(size_t)(cg     ) * P + p0n + 2 * pp];  \
        FV1 = *(const float2*)&pf_b[(size_t)(cg +  8) * P + p0n + 2 * pp];  \
        FV2 = *(const float2*)&pf_b[(size_t)(cg + 16) * P + p0n + 2 * pp];  \
        FV3 = *(const float2*)&pf_b[(size_t)(cg + 24) * P + p0n + 2 * pp];  \
    }

#define SCATTER_STAGE(IDXR, WV0, WV1, WV2, FV0, FV1, FV2, FV3)              \
    {                                                                       \
        const int iy  = (IDXR) / nw;                                        \
        const int ixx = (IDXR) - iy * nw;                                   \
        const float wvv[3] = {WV0, WV1, WV2};                               \
        _Pragma("unroll")                                                   \
        for (int wi = 0; wi < 3; ++wi) {                                    \
            const int j = grp + 4 * wi;                                     \
            if (j >= 9) continue;                                           \
            const int ty = iy + j / 3 - 1;                                  \
            const int tx = ixx + j % 3 - 1;                                 \
            if (tx < 0 || tx >= nw || ty < 0 || ty >= nh) continue;         \
            const int t   = ty * nw + tx;                                   \
            const int off = ((((t >> 4) * SPS + psx) * 64                   \
                              + (t & 15) + ((q >> 3) << 4)) * 8) + (q & 7); \
            lsA[off] = (short)bf16_1(wvv[wi]);                              \
        }                                                                   \
        const float2 fvv[4] = {FV0, FV1, FV2, FV3};                         \
        _Pragma("unroll")                                                   \
        for (int ci = 0; ci < 4; ++ci) {                                    \
            const int c   = cg + 8 * ci;                                    \
            const int off = ((((c >> 4) * SPS + (p2 >> 5)) * 64             \
                              + (c & 15) + ((q2 >> 3) << 4)) * 8) + (q2&7); \
            *(unsigned*)&lsB[off] = pack_bf16(fvv[ci].x, fvv[ci].y);        \
        }                                                                   \
    }

// MFMA phase with reader-zero: wave w owns k-tiles 2w, 2w+1; after reading
// an A-fragment it writes b128 zeros back (same-wave DS ops are in-order;
// each A-region has exactly one reader wave -> race-free, no extra barrier).
#define MFMA_PHASE_Z()                                                      \
    _Pragma("unroll")                                                       \
    for (int ps = 0; ps < SPS; ++ps) {                                      \
        int4v bfr[3];                                                       \
        _Pragma("unroll")                                                   \
        for (int ct = 0; ct < 3; ++ct)                                      \
            bfr[ct] = *(int4v*)&lsB[((ct * SPS + ps) * 64 + lane) * 8];     \
        _Pragma("unroll")                                                   \
        for (int ktl = 0; ktl < 2; ++ktl) {                                 \
            const int kt  = wave * 2 + ktl;                                 \
            const int aix = ((kt * SPS + ps) * 64 + lane) * 8;              \
            int4v af = *(int4v*)&lsA[aix];                                  \
            _Pragma("unroll")                                               \
            for (int ct = 0; ct < 3; ++ct) {                                \
                asm("v_mfma_f32_16x16x32_bf16 %0, %1, %2, %0"               \
                    : "+v"(acc[ktl][ct])                                    \
                    : "v"(af), "v"(bfr[ct]));                               \
            }                                                               \
            *(int4v*)&lsA[aix] = (int4v){0, 0, 0, 0};                       \
        }                                                                   \
    }

__global__ __launch_bounds__(512, 4) void spx_mfma_kernel(
    const float* __restrict__ pf,      // [B][C][P]
    const float* __restrict__ assoc,   // [B][9][P]
    const int*   __restrict__ idxmap,  // [B][P]
    const int*   __restrict__ nw_p,
    const int*   __restrict__ nh_p,
    float*       __restrict__ part,    // [B*bpbk][KFS] block partials
    int P, int K, int cpb, int bpbk)   // chunks/block (EVEN), blocks/batch
{
    __shared__ __align__(16) short lsA[16 * SPS * 64 * 8];  // 64 KB
    __shared__ __align__(16) short lsB[3 * SPS * 64 * 8];   // 12 KB

    const int tid  = threadIdx.x;
    const int wave = tid >> 6;
    const int lane = tid & 63;
    const int b    = blockIdx.x / bpbk;
    const int blkb = blockIdx.x - b * bpbk;

    const int nw = nw_p[0], nh = nh_p[0];

    // prologue: full zero of lsA ONCE (steady-state zeroing is reader-zero),
    // static ones c-tile of lsB (regions 8..11: B[p][32]=1, 33..47=0)
#pragma unroll
    for (int i = 0; i < 8; ++i)
        *(uint4*)&lsA[(tid + 512 * i) * 8] = make_uint4(0u, 0u, 0u, 0u);
    if (tid < 256) {
        const int reg = 2 * SPS + (tid >> 6);
        const int ln  = tid & 63;
        uint4 v = ((ln & 15) == 0)
            ? make_uint4(0x3F803F80u, 0x3F803F80u, 0x3F803F80u, 0x3F803F80u)
            : make_uint4(0u, 0u, 0u, 0u);
        *(uint4*)&lsB[(reg * 64 + ln) * 8] = v;
    }

    const int*   ix_b = idxmap + (size_t)b * P;
    const float* pf_b = pf     + (size_t)b * CCH * P;
    const float* as_b = assoc  + (size_t)b * 9 * P;

    f32x4 acc[2][3];
#pragma unroll
    for (int i = 0; i < 2; ++i)
#pragma unroll
        for (int j = 0; j < 3; ++j) acc[i][j] = f32x4{0.f, 0.f, 0.f, 0.f};

    const int grp = tid >> 7;      // j-group 0..3
    const int pl  = tid & 127;     // scatter pixel 0..127
    const int pp  = tid & 63;      // pixel-pair index for F staging
    const int cg  = tid >> 6;      // channel group 0..7
    const int q   = pl & 31;
    const int psx = pl >> 5;       // px-subtile of the scatter pixel
    const int p2  = 2 * pp;
    const int q2  = p2 & 31;

    // depth-2 prefetch: two static register sets
    int    idxA, idxB2;
    float  wA0, wA1, wA2, wB0, wB1, wB2;
    float2 fA0, fA1, fA2, fA3, fB0, fB1, fB2, fB3;

    PF_CHUNK(0, idxA, wA0, wA1, wA2, fA0, fA1, fA2, fA3);
    PF_CHUNK(1, idxB2, wB0, wB1, wB2, fB0, fB1, fB2, fB3);

    wg_barrier();   // zero + ones visible before first scatter

    for (int ch = 0; ch < cpb; ch += 2) {
        // ---- even chunk (set A) ----
        SCATTER_STAGE(idxA, wA0, wA1, wA2, fA0, fA1, fA2, fA3);
        {   // prefetch ch+2 (consumed 2 chunk-pipelines later)
            const int chn = (ch + 2 < cpb) ? ch + 2 : cpb - 1;
            PF_CHUNK(chn, idxA, wA0, wA1, wA2, fA0, fA1, fA2, fA3);
        }
        wg_barrier();
        MFMA_PHASE_Z();
        wg_barrier();

        // ---- odd chunk (set B) ----
        SCATTER_STAGE(idxB2, wB0, wB1, wB2, fB0, fB1, fB2, fB3);
        {
            const int chn = (ch + 3 < cpb) ? ch + 3 : cpb - 1;
            PF_CHUNK(chn, idxB2, wB0, wB1, wB2, fB0, fB1, fB2, fB3);
        }
        wg_barrier();
        MFMA_PHASE_Z();
        wg_barrier();
    }

    // MFMA -> VALU read hazard guard before the flush reads acc
    asm volatile("s_nop 7\n\ts_nop 7");

    // flush: plain streaming stores of this block's partial (no atomics)
    float* pb = part + (size_t)(b * bpbk + blkb) * KFS;
    const int col = lane & 15;
    const int rw0 = (lane >> 4) * 4;
#pragma unroll
    for (int ktl = 0; ktl < 2; ++ktl) {
        const int kt = wave * 2 + ktl;
#pragma unroll
        for (int ct = 0; ct < 3; ++ct) {
            const int c = ct * 16 + col;
            if (c > CCH) continue;      // ct=2: only col 0 (wsum) is real
#pragma unroll
            for (int i = 0; i < 4; ++i) {
                const int k = kt * 16 + rw0 + i;
                pb[(size_t)k * FST + c] = acc[ktl][ct][i];
            }
        }
    }
}

// Fused reduce+divide. Block (b,g) owns 4 bins = 132 consecutive floats
// (132*64 == KFS). Wave w lane l sums cols {l, 64+l, 128+l(<4)} over
// partials blk = w+4m (256B coalesced wave-loads, 6 loads in flight via
// 2-unroll), LDS cross-wave combine, then in-block division + out write.
__global__ __launch_bounds__(256) void spx_reduce_div_kernel(
    const float* __restrict__ part,   // [B*bpbk][KFS]
    float*       __restrict__ out,    // [B][C][K]
    int K, int bpbk)
{
    __shared__ float red[4][4 * FST];  // [wave][132]

    const int gpb = KMAX / 4;          // 64 groups per batch
    const int b   = blockIdx.x / gpb;
    const int g   = blockIdx.x - b * gpb;
    const int w   = threadIdx.x >> 6;
    const int l   = threadIdx.x & 63;

    const float* p = part + (size_t)b * bpbk * KFS + g * (4 * FST);
    const int n = bpbk >> 2;           // partials per wave
    float s0 = 0.f, s1 = 0.f, s2 = 0.f;
    for (int m = 0; m < n; m += 2) {
        const float* r0 = p + (size_t)(w + 4 * m) * KFS;
        const float* r1 = p + (size_t)(w + 4 * (m + 1)) * KFS;
        const float a0 = r0[l], a1 = r0[64 + l];
        const float a2 = (l < 4) ? r0[128 + l] : 0.f;
        const float b0 = r1[l], b1 = r1[64 + l];
        const float b2 = (l < 4) ? r1[128 + l] : 0.f;
        s0 += a0 + b0; s1 += a1 + b1; s2 += a2 + b2;
    }
    red[w][l] = s0;
    red[w][64 + l] = s1;
    if (l < 4) red[w][128 + l] = s2;
    __syncthreads();

    if (threadIdx.x < 128) {
        const int c  = threadIdx.x >> 2;   // 0..31
        const int lb = threadIdx.x & 3;    // local bin 0..3
        const float W = red[0][lb * FST + CCH] + red[1][lb * FST + CCH]
                      + red[2][lb * FST + CCH] + red[3][lb * FST + CCH];
        const float v = red[0][lb * FST + c] + red[1][lb * FST + c]
                      + red[2][lb * FST + c] + red[3][lb * FST + c];
        out[((size_t)b * CCH + c) * K + g * 4 + lb] =
            (W > 1e-16f) ? v / W : 0.f;
    }
}

extern "C" void kernel_launch(void* const* d_in, const int* in_sizes, int n_in,
                              void* d_out, int out_size, void* d_ws, size_t ws_size,
                              hipStream_t stream) {
    const float* pf     = (const float*)d_in[0];
    const float* assoc  = (const float*)d_in[1];
    const int*   idxmap = (const int*)d_in[2];
    const int*   nw_p   = (const int*)d_in[3];
    const int*   nh_p   = (const int*)d_in[4];
    float* out = (float*)d_out;

    const int BP = in_sizes[2];          // B*P = 262144
    const int B  = 4;                    // fixed by reference setup
    const int P  = BP / B;               // 65536
    const int K  = out_size / (B * CCH); // 256 (== KMAX)

    // ws: part [B*bpbk][KFS] only (17.3 MB at bpbk=128)
    int bpbk = 128;                      // 512 blocks -> 2 blocks/CU
    while ((size_t)B * bpbk * KFS * sizeof(float) > ws_size && bpbk > 32)
        bpbk >>= 1;
    const int cpb = (P / PXC) / bpbk;    // 4 (even; fallbacks 8/16 even too)
    float* part = (float*)d_ws;

    spx_mfma_kernel<<<B * bpbk, 512, 0, stream>>>(
        pf, assoc, idxmap, nw_p, nh_p, part, P, K, cpb, bpbk);

    spx_reduce_div_kernel<<<B * (KMAX / 4), 256, 0, stream>>>(
        part, out, K, bpbk);
}